// Round 2
// baseline (272.074 us; speedup 1.0000x reference)
//
#include <hip/hip_runtime.h>
#include <math.h>

#define NB 8
#define NN 2048
#define IN_DIM 256
#define OUT_DIM 64
#define ALPHA 0.2f
#define JSPLIT 4

typedef __attribute__((ext_vector_type(8))) short bf16x8;
typedef __attribute__((ext_vector_type(4))) float f32x4;
typedef __attribute__((ext_vector_type(4))) int i32x4;
typedef __attribute__((ext_vector_type(4))) unsigned u32x4;

// float -> bf16 (RNE), bit trick (no NaN inputs here)
__device__ __forceinline__ unsigned short f2bf(float x) {
    union { float f; unsigned u; } v; v.f = x;
    unsigned r = v.u + 0x7FFF + ((v.u >> 16) & 1);
    return (unsigned short)(r >> 16);
}

// pack 2 f32 -> 2 bf16 (RNE), single HW instr; numerically == f2bf
__device__ __forceinline__ unsigned cvt_pk_bf16(float lo, float hi) {
    unsigned r;
    asm("v_cvt_pk_bf16_f32 %0, %1, %2" : "=v"(r) : "v"(lo), "v"(hi));
    return r;
}

// ---------------------------------------------------------------------------
// Kernel 0: pack adj (int32 in {0,1}) -> bitmask, 32x compression.
// Pure stream: 134 MB read (nontemporal) -> 4.2 MB write, ~90% HBM peak.
// One wave = one row of 2048: lane L packs j = 32L..32L+31 into one dword.
// Bit k of mask[r*64+L] = adj[r][32L+k] (exact: adj values are 0/1).
// ---------------------------------------------------------------------------
__global__ __launch_bounds__(256) void pack_kernel(const int* __restrict__ adj,
                                                   unsigned* __restrict__ mask) {
    const int t = threadIdx.x, lane = t & 63, wv = t >> 6;
    const int r = blockIdx.x * 4 + wv;                 // 0..NB*NN-1
    const int* ap = adj + (long)r * NN + lane * 32;
    unsigned bits = 0;
    #pragma unroll
    for (int u = 0; u < 8; ++u) {
        const i32x4 v = __builtin_nontemporal_load((const i32x4*)(ap + 4 * u));
        bits |= (unsigned)(v[0] & 1) << (4 * u + 0);
        bits |= (unsigned)(v[1] & 1) << (4 * u + 1);
        bits |= (unsigned)(v[2] & 1) << (4 * u + 2);
        bits |= (unsigned)(v[3] & 1) << (4 * u + 3);
    }
    mask[r * 64 + lane] = bits;
}

// ---------------------------------------------------------------------------
// Kernel 1: Wh = h@W via bf16 MFMA. Outputs: Whbt (bf16, layout [b][d][j] so
// kernel-2 B-frags are 16B contiguous per lane), s1 = Wh@a1, s2 = Wh@a2.
// ---------------------------------------------------------------------------
#define WT_STRIDE 264   // bf16 elems; 528B rows (16B aligned)
__global__ __launch_bounds__(256) void wh_kernel(const float* __restrict__ h,
                                                 const float* __restrict__ W,
                                                 const float* __restrict__ a,
                                                 unsigned short* __restrict__ Whbt,
                                                 float* __restrict__ s1,
                                                 float* __restrict__ s2) {
    __shared__ unsigned short Wt[OUT_DIM * WT_STRIDE];   // ~33 KB
    const int t = threadIdx.x;

    // stage W (coalesced f32 reads) -> Wt[n][k] bf16
    #pragma unroll 8
    for (int rep = 0; rep < 64; ++rep) {
        const int id = rep * 256 + t;          // 0..16383
        const int k = id >> 6, n = id & 63;
        Wt[n * WT_STRIDE + k] = f2bf(W[id]);
    }
    __syncthreads();

    const int lane = t & 63, wv = t >> 6;
    const int m = lane & 15, quad = lane >> 4;
    const long gr0 = (long)(blockIdx.x * 4 + wv) * 16;   // global row base

    f32x4 acc[4];
    #pragma unroll
    for (int nt = 0; nt < 4; ++nt) acc[nt] = (f32x4){0.f, 0.f, 0.f, 0.f};

    #pragma unroll
    for (int ks = 0; ks < 8; ++ks) {
        const int k0 = ks * 32;
        // A-frag: h[i = gr0+m][k0 + quad*8 .. +7]  (per-lane distinct, 32B)
        const float* hp = h + (gr0 + m) * IN_DIM + k0 + quad * 8;
        const float4 ha = *(const float4*)hp;
        const float4 hb = *(const float4*)(hp + 4);
        union { bf16x8 v; unsigned u32[4]; } af;
        af.u32[0] = cvt_pk_bf16(ha.x, ha.y);
        af.u32[1] = cvt_pk_bf16(ha.z, ha.w);
        af.u32[2] = cvt_pk_bf16(hb.x, hb.y);
        af.u32[3] = cvt_pk_bf16(hb.z, hb.w);
        #pragma unroll
        for (int nt = 0; nt < 4; ++nt) {
            const bf16x8 bf_ = *(const bf16x8*)(const void*)
                &Wt[(nt * 16 + m) * WT_STRIDE + k0 + quad * 8];
            acc[nt] = __builtin_amdgcn_mfma_f32_16x16x32_bf16(af.v, bf_, acc[nt], 0, 0, 0);
        }
    }

    // ---- epilogue.  C layout: col=lane&15 (d within tile), row=quad*4+reg (i) ----
    const int b  = (int)(gr0 >> 11);
    const int ib = (int)(gr0 & 2047);          // within-batch row base

    #pragma unroll
    for (int nt = 0; nt < 4; ++nt) {
        ushort4 w4;
        w4.x = f2bf(acc[nt][0]); w4.y = f2bf(acc[nt][1]);
        w4.z = f2bf(acc[nt][2]); w4.w = f2bf(acc[nt][3]);
        *(ushort4*)&Whbt[((long)(b * OUT_DIM + nt * 16 + m) << 11) + ib + quad * 4] = w4;
    }

    float a1v[4], a2v[4];
    #pragma unroll
    for (int nt = 0; nt < 4; ++nt) {
        a1v[nt] = a[nt * 16 + m];
        a2v[nt] = a[OUT_DIM + nt * 16 + m];
    }
    #pragma unroll
    for (int reg = 0; reg < 4; ++reg) {
        float p1 = 0.f, p2 = 0.f;
        #pragma unroll
        for (int nt = 0; nt < 4; ++nt) {
            p1 += acc[nt][reg] * a1v[nt];
            p2 += acc[nt][reg] * a2v[nt];
        }
        #pragma unroll
        for (int off = 1; off < 16; off <<= 1) {
            p1 += __shfl_xor(p1, off, 64);
            p2 += __shfl_xor(p2, off, 64);
        }
        if (m == 0) {
            s1[gr0 + quad * 4 + reg] = p1;
            s2[gr0 + quad * 4 + reg] = p2;
        }
    }
}

// ---------------------------------------------------------------------------
// Kernel 2: masked softmax + P@Wh via bf16 MFMA.  adj replaced by the packed
// bitmask: each lane preloads its ENTIRE 16-step mask slice (16 dwords) into
// registers before the loop -> zero adj-related VMEM in the inner loop.
// Remaining in-loop VMEM: 4 B-frags (Whbt, L2-hot) + 2 s2 loads, both
// prefetched one step ahead.  P computed directly in A-frag lane layout.
// Grid: NB * (NN/64) * JSPLIT = 1024 blocks x 4 waves; zero barriers, no LDS.
// ---------------------------------------------------------------------------
__global__ __launch_bounds__(256) void attn_kernel(const unsigned* __restrict__ mask,
                                                   const unsigned short* __restrict__ Whbt,
                                                   const float* __restrict__ s1,
                                                   const float* __restrict__ s2,
                                                   float* __restrict__ part,
                                                   float* __restrict__ lpart) {
    const int t = threadIdx.x, lane = t & 63, wv = t >> 6;

    const int bid = blockIdx.x;
    const int js  = bid & (JSPLIT - 1);
    const int itg = (bid >> 2) & 31;
    const int b   = bid >> 7;
    const int i0  = itg * 64 + wv * 16;       // within-batch row base (16 rows)
    const int jlo = js * (NN / JSPLIT);       // 512-wide j slice

    const int m = lane & 15, quad = lane >> 4;   // MFMA lane map

    const float s1v = s1[b * NN + i0 + m];

    // mask slice for this lane's row: dwords [js*16 .. js*16+15] of row i0+m
    const unsigned* mrowp = mask + ((long)(b * NN + i0 + m) << 6) + (js << 4);
    u32x4 md[4];
    #pragma unroll
    for (int d = 0; d < 4; ++d) md[d] = *(const u32x4*)(mrowp + 4 * d);

    f32x4 acc[4];
    #pragma unroll
    for (int nt = 0; nt < 4; ++nt) acc[nt] = (f32x4){0.f, 0.f, 0.f, 0.f};
    float lacc = 0.f;

    const float* s2p = s2 + b * NN + jlo + quad * 8;
    const unsigned short* wbase = Whbt + ((long)(b * OUT_DIM) << 11) + jlo + quad * 8;

    // prefetch step 0
    f32x4 sv0 = *(const f32x4*)s2p;
    f32x4 sv1 = *(const f32x4*)(s2p + 4);
    bf16x8 bn[4];
    #pragma unroll
    for (int nt = 0; nt < 4; ++nt)
        bn[nt] = *(const bf16x8*)(const void*)&wbase[(long)(nt * 16 + m) << 11];

    const int NSTEP = NN / JSPLIT / 32;       // 16
    #pragma unroll
    for (int ks = 0; ks < NSTEP; ++ks) {
        const int j0 = ks * 32;
        const int jn = (ks + 1 < NSTEP) ? j0 + 32 : j0;

        // grab current operands
        const f32x4 t0 = sv0, t1 = sv1;
        bf16x8 bc[4];
        #pragma unroll
        for (int nt = 0; nt < 4; ++nt) bc[nt] = bn[nt];

        // issue next step's prefetch (covers L2 latency under this step's VALU)
        sv0 = *(const f32x4*)(s2p + jn);
        sv1 = *(const f32x4*)(s2p + jn + 4);
        #pragma unroll
        for (int nt = 0; nt < 4; ++nt)
            bn[nt] = *(const bf16x8*)(const void*)
                &wbase[((long)(nt * 16 + m) << 11) + jn];

        // mask bits for this lane's 8 j's (register-resident, static index)
        const unsigned mdw  = md[ks >> 2][ks & 3];
        const unsigned byte8 = (mdw >> (quad * 8)) & 0xffu;

        float p[8];
        #pragma unroll
        for (int u = 0; u < 8; ++u) {
            float e = s1v + (u < 4 ? t0[u] : t1[u - 4]);
            e = fmaxf(e, ALPHA * e);            // leaky_relu, branchless
            const float ex = __expf(e);
            p[u] = ((byte8 >> u) & 1u) ? ex : 0.f;
        }
        lacc += ((p[0] + p[1]) + (p[2] + p[3])) + ((p[4] + p[5]) + (p[6] + p[7]));

        union { bf16x8 v; unsigned u32[4]; } af;
        af.u32[0] = cvt_pk_bf16(p[0], p[1]);
        af.u32[1] = cvt_pk_bf16(p[2], p[3]);
        af.u32[2] = cvt_pk_bf16(p[4], p[5]);
        af.u32[3] = cvt_pk_bf16(p[6], p[7]);

        #pragma unroll
        for (int nt = 0; nt < 4; ++nt)
            acc[nt] = __builtin_amdgcn_mfma_f32_16x16x32_bf16(af.v, bc[nt], acc[nt], 0, 0, 0);
    }

    // ---- l partials: reduce over the 4 quads (row = m) ----
    lacc += __shfl_xor(lacc, 16, 64);
    lacc += __shfl_xor(lacc, 32, 64);
    if (quad == 0)
        lpart[js * (NB * NN) + b * NN + i0 + m] = lacc;

    // ---- out partials.  C layout: i = i0+quad*4+reg, d = nt*16+m ----
    float* pp = part + (long)js * ((long)NB * NN * OUT_DIM)
                     + ((long)(b * NN + i0) << 6);
    #pragma unroll
    for (int nt = 0; nt < 4; ++nt)
        #pragma unroll
        for (int reg = 0; reg < 4; ++reg)
            pp[(quad * 4 + reg) * OUT_DIM + nt * 16 + m] = acc[nt][reg];
}

// ---------------------------------------------------------------------------
// Kernel 3: out = (sum_js part) / (sum_js lpart), float4 coalesced.
// ---------------------------------------------------------------------------
__global__ __launch_bounds__(256) void finalize_kernel(const float* __restrict__ part,
                                                       const float* __restrict__ lpart,
                                                       float* __restrict__ out) {
    const int idx = blockIdx.x * 256 + threadIdx.x;   // float4 index
    const int row = idx >> 4;
    float l = 0.f;
    #pragma unroll
    for (int s = 0; s < JSPLIT; ++s) l += lpart[s * (NB * NN) + row];
    float4 v = make_float4(0.f, 0.f, 0.f, 0.f);
    const float4* p4 = (const float4*)part;
    #pragma unroll
    for (int s = 0; s < JSPLIT; ++s) {
        const float4 p = p4[(long)s * ((long)NB * NN * OUT_DIM / 4) + idx];
        v.x += p.x; v.y += p.y; v.z += p.z; v.w += p.w;
    }
    const float inv = 1.f / l;
    v.x *= inv; v.y *= inv; v.z *= inv; v.w *= inv;
    ((float4*)out)[idx] = v;
}

// ---------------------------------------------------------------------------
extern "C" void kernel_launch(void* const* d_in, const int* in_sizes, int n_in,
                              void* d_out, int out_size, void* d_ws, size_t ws_size,
                              hipStream_t stream) {
    const float* h   = (const float*)d_in[0];
    const int*   adj = (const int*)d_in[1];
    const float* W   = (const float*)d_in[2];
    const float* a   = (const float*)d_in[3];
    float* out = (float*)d_out;

    float* s1    = (float*)d_ws;                         // 16K f32
    float* s2    = s1 + NB * NN;                         // 16K f32
    float* lpart = s2 + NB * NN;                         // 64K f32
    float* part  = lpart + JSPLIT * NB * NN;             // 4M f32 = 16 MB
    unsigned short* Whbt = (unsigned short*)(part + (long)JSPLIT * NB * NN * OUT_DIM); // 1M bf16 = 2 MB
    unsigned* mask = (unsigned*)(Whbt + (long)NB * OUT_DIM * NN);  // 1M u32 = 4 MB

    pack_kernel<<<NB * NN / 4, 256, 0, stream>>>(adj, mask);
    wh_kernel<<<NB * NN / 64, 256, 0, stream>>>(h, W, a, Whbt, s1, s2);
    attn_kernel<<<NB * (NN / 64) * JSPLIT, 256, 0, stream>>>(mask, Whbt, s1, s2, part, lpart);
    finalize_kernel<<<NB * NN * OUT_DIM / 4 / 256, 256, 0, stream>>>(part, lpart, out);
}

// Round 3
// 236.562 us; speedup vs baseline: 1.1501x; 1.1501x over previous
//
#include <hip/hip_runtime.h>
#include <math.h>

#define NB 8
#define NN 2048
#define IN_DIM 256
#define OUT_DIM 64
#define ALPHA 0.2f

typedef __attribute__((ext_vector_type(8))) short bf16x8;
typedef __attribute__((ext_vector_type(4))) float f32x4;
typedef __attribute__((ext_vector_type(4))) int i32x4;

// float -> bf16 (RNE), bit trick (no NaN inputs here)
__device__ __forceinline__ unsigned short f2bf(float x) {
    union { float f; unsigned u; } v; v.f = x;
    unsigned r = v.u + 0x7FFF + ((v.u >> 16) & 1);
    return (unsigned short)(r >> 16);
}

// pack 2 f32 -> 2 bf16 (RNE), single HW instr; numerically == f2bf
__device__ __forceinline__ unsigned cvt_pk_bf16(float lo, float hi) {
    unsigned r;
    asm("v_cvt_pk_bf16_f32 %0, %1, %2" : "=v"(r) : "v"(lo), "v"(hi));
    return r;
}

// ---------------------------------------------------------------------------
// Kernel 1: Wh = h@W via bf16 MFMA. Outputs: Whbt (bf16, layout [b][d][j] so
// kernel-2 B-frags are 16B contiguous per lane), s1 = Wh@a1, s2 = Wh@a2.
// Grid 256 blocks x 256 thr; wave = one 16-row i-tile, block = 64 rows.
// ---------------------------------------------------------------------------
#define WT_STRIDE 264   // bf16 elems; 528B rows (16B aligned)
__global__ __launch_bounds__(256) void wh_kernel(const float* __restrict__ h,
                                                 const float* __restrict__ W,
                                                 const float* __restrict__ a,
                                                 unsigned short* __restrict__ Whbt,
                                                 float* __restrict__ s1,
                                                 float* __restrict__ s2) {
    __shared__ unsigned short Wt[OUT_DIM * WT_STRIDE];   // ~33 KB
    const int t = threadIdx.x;

    // stage W (coalesced f32 reads) -> Wt[n][k] bf16
    #pragma unroll 8
    for (int rep = 0; rep < 64; ++rep) {
        const int id = rep * 256 + t;          // 0..16383
        const int k = id >> 6, n = id & 63;
        Wt[n * WT_STRIDE + k] = f2bf(W[id]);
    }
    __syncthreads();

    const int lane = t & 63, wv = t >> 6;
    const int m = lane & 15, quad = lane >> 4;
    const long gr0 = (long)(blockIdx.x * 4 + wv) * 16;   // global row base

    f32x4 acc[4];
    #pragma unroll
    for (int nt = 0; nt < 4; ++nt) acc[nt] = (f32x4){0.f, 0.f, 0.f, 0.f};

    #pragma unroll
    for (int ks = 0; ks < 8; ++ks) {
        const int k0 = ks * 32;
        // A-frag: h[i = gr0+m][k0 + quad*8 .. +7]  (per-lane distinct, 32B)
        const float* hp = h + (gr0 + m) * IN_DIM + k0 + quad * 8;
        const float4 ha = *(const float4*)hp;
        const float4 hb = *(const float4*)(hp + 4);
        union { bf16x8 v; unsigned u32[4]; } af;
        af.u32[0] = cvt_pk_bf16(ha.x, ha.y);
        af.u32[1] = cvt_pk_bf16(ha.z, ha.w);
        af.u32[2] = cvt_pk_bf16(hb.x, hb.y);
        af.u32[3] = cvt_pk_bf16(hb.z, hb.w);
        #pragma unroll
        for (int nt = 0; nt < 4; ++nt) {
            const bf16x8 bf_ = *(const bf16x8*)(const void*)
                &Wt[(nt * 16 + m) * WT_STRIDE + k0 + quad * 8];
            acc[nt] = __builtin_amdgcn_mfma_f32_16x16x32_bf16(af.v, bf_, acc[nt], 0, 0, 0);
        }
    }

    // ---- epilogue.  C layout: col=lane&15 (d within tile), row=quad*4+reg (i) ----
    const int b  = (int)(gr0 >> 11);
    const int ib = (int)(gr0 & 2047);          // within-batch row base

    #pragma unroll
    for (int nt = 0; nt < 4; ++nt) {
        ushort4 w4;
        w4.x = f2bf(acc[nt][0]); w4.y = f2bf(acc[nt][1]);
        w4.z = f2bf(acc[nt][2]); w4.w = f2bf(acc[nt][3]);
        *(ushort4*)&Whbt[((long)(b * OUT_DIM + nt * 16 + m) << 11) + ib + quad * 4] = w4;
    }

    float a1v[4], a2v[4];
    #pragma unroll
    for (int nt = 0; nt < 4; ++nt) {
        a1v[nt] = a[nt * 16 + m];
        a2v[nt] = a[OUT_DIM + nt * 16 + m];
    }
    #pragma unroll
    for (int reg = 0; reg < 4; ++reg) {
        float p1 = 0.f, p2 = 0.f;
        #pragma unroll
        for (int nt = 0; nt < 4; ++nt) {
            p1 += acc[nt][reg] * a1v[nt];
            p2 += acc[nt][reg] * a2v[nt];
        }
        #pragma unroll
        for (int off = 1; off < 16; off <<= 1) {
            p1 += __shfl_xor(p1, off, 64);
            p2 += __shfl_xor(p2, off, 64);
        }
        if (m == 0) {
            s1[gr0 + quad * 4 + reg] = p1;
            s2[gr0 + quad * 4 + reg] = p2;
        }
    }
}

// ---------------------------------------------------------------------------
// Kernel 2: masked softmax + P@Wh via bf16 MFMA, FULLY FUSED:
//   - one block = one 16-row i-tile; its 4 waves split j 4-ways (512 each)
//   - adj read directly (once, nontemporal, coalesced) — no packing
//   - P computed in-register in the MFMA A-frag lane layout (no per-step LDS)
//   - block-level reduction of acc & l through 17 KB LDS (one barrier),
//     then divide and write `out` DIRECTLY — no part/lpart/finalize.
// Grid: NB * (NN/16) = 1024 blocks x 256 thr (16 waves/CU, same as R0).
// ---------------------------------------------------------------------------
#define AB_STRIDE 68   // f32 elems per acc row; 272B (16B aligned, bank-shift 4)
__global__ __launch_bounds__(256) void attn_kernel(const int* __restrict__ adj,
                                                   const unsigned short* __restrict__ Whbt,
                                                   const float* __restrict__ s1,
                                                   const float* __restrict__ s2,
                                                   float* __restrict__ out) {
    __shared__ float accbuf[4][16 * AB_STRIDE];   // 4 waves x 16 rows x 64 d
    __shared__ float l_lds[4][16];

    const int t = threadIdx.x, lane = t & 63, wv = t >> 6;
    const int bid = blockIdx.x;
    const int b   = bid >> 7;                 // 128 tiles per batch
    const int i0  = (bid & 127) * 16;         // within-batch row base (16 rows)
    const int jlo = wv * (NN / 4);            // this wave's 512-wide j slice

    const int m = lane & 15, quad = lane >> 4;   // MFMA lane map

    const float s1v = s1[b * NN + i0 + m];

    f32x4 acc[4];
    #pragma unroll
    for (int nt = 0; nt < 4; ++nt) acc[nt] = (f32x4){0.f, 0.f, 0.f, 0.f};
    float lacc = 0.f;

    const int* adjp = adj + (long)b * NN * NN + (long)(i0 + m) * NN + jlo + quad * 8;
    const float* s2p = s2 + b * NN + jlo + quad * 8;
    const unsigned short* wbase = Whbt + ((long)(b * OUT_DIM) << 11) + jlo + quad * 8;

    // prefetch step 0 (adj nontemporal: streamed once, keep Whbt L2-resident)
    i32x4 av0 = __builtin_nontemporal_load((const i32x4*)adjp);
    i32x4 av1 = __builtin_nontemporal_load((const i32x4*)(adjp + 4));
    f32x4 sv0 = *(const f32x4*)s2p;
    f32x4 sv1 = *(const f32x4*)(s2p + 4);
    bf16x8 bn[4];
    #pragma unroll
    for (int nt = 0; nt < 4; ++nt)
        bn[nt] = *(const bf16x8*)(const void*)&wbase[(long)(nt * 16 + m) << 11];

    const int NSTEP = NN / 4 / 32;            // 16
    for (int ks = 0; ks < NSTEP; ++ks) {
        const int j0 = ks * 32;
        const int jn = (ks + 1 < NSTEP) ? j0 + 32 : j0;

        // grab current operands
        const i32x4 a0 = av0, a1 = av1;
        const f32x4 t0 = sv0, t1 = sv1;
        bf16x8 bc[4];
        #pragma unroll
        for (int nt = 0; nt < 4; ++nt) bc[nt] = bn[nt];

        // issue next step's prefetch (in flight under this step's VALU+MFMA)
        av0 = __builtin_nontemporal_load((const i32x4*)(adjp + jn));
        av1 = __builtin_nontemporal_load((const i32x4*)(adjp + jn + 4));
        sv0 = *(const f32x4*)(s2p + jn);
        sv1 = *(const f32x4*)(s2p + jn + 4);
        #pragma unroll
        for (int nt = 0; nt < 4; ++nt)
            bn[nt] = *(const bf16x8*)(const void*)
                &wbase[((long)(nt * 16 + m) << 11) + jn];

        // P for this lane's 8 j's, directly in A-frag order
        float p[8];
        #pragma unroll
        for (int u = 0; u < 4; ++u) {
            float e = s1v + t0[u];
            e = fmaxf(e, ALPHA * e);            // leaky_relu, branchless
            const float ex = __expf(e);
            p[u] = (a0[u] != 0) ? ex : 0.f;
        }
        #pragma unroll
        for (int u = 0; u < 4; ++u) {
            float e = s1v + t1[u];
            e = fmaxf(e, ALPHA * e);
            const float ex = __expf(e);
            p[4 + u] = (a1[u] != 0) ? ex : 0.f;
        }
        lacc += ((p[0] + p[1]) + (p[2] + p[3])) + ((p[4] + p[5]) + (p[6] + p[7]));

        union { bf16x8 v; unsigned u32[4]; } af;
        af.u32[0] = cvt_pk_bf16(p[0], p[1]);
        af.u32[1] = cvt_pk_bf16(p[2], p[3]);
        af.u32[2] = cvt_pk_bf16(p[4], p[5]);
        af.u32[3] = cvt_pk_bf16(p[6], p[7]);

        #pragma unroll
        for (int nt = 0; nt < 4; ++nt)
            acc[nt] = __builtin_amdgcn_mfma_f32_16x16x32_bf16(af.v, bc[nt], acc[nt], 0, 0, 0);
    }

    // ---- per-wave l: reduce over the 4 quads (row = m) ----
    lacc += __shfl_xor(lacc, 16, 64);
    lacc += __shfl_xor(lacc, 32, 64);
    if (quad == 0) l_lds[wv][m] = lacc;

    // ---- stage this wave's acc tile.  C layout: row=quad*4+reg, d=nt*16+m ----
    #pragma unroll
    for (int nt = 0; nt < 4; ++nt)
        #pragma unroll
        for (int reg = 0; reg < 4; ++reg)
            accbuf[wv][(quad * 4 + reg) * AB_STRIDE + nt * 16 + m] = acc[nt][reg];

    __syncthreads();

    // ---- block reduce + divide + direct out write (thread t -> 4 floats) ----
    const int row = t >> 4, d0 = (t & 15) * 4;
    f32x4 v = (f32x4){0.f, 0.f, 0.f, 0.f};
    float l = 0.f;
    #pragma unroll
    for (int w2 = 0; w2 < 4; ++w2) {
        v += *(const f32x4*)&accbuf[w2][row * AB_STRIDE + d0];
        l += l_lds[w2][row];
    }
    const float inv = 1.f / l;
    float4 o; o.x = v[0] * inv; o.y = v[1] * inv; o.z = v[2] * inv; o.w = v[3] * inv;
    *(float4*)&out[((long)(b * NN + i0 + row) << 6) + d0] = o;
}

// ---------------------------------------------------------------------------
extern "C" void kernel_launch(void* const* d_in, const int* in_sizes, int n_in,
                              void* d_out, int out_size, void* d_ws, size_t ws_size,
                              hipStream_t stream) {
    const float* h   = (const float*)d_in[0];
    const int*   adj = (const int*)d_in[1];
    const float* W   = (const float*)d_in[2];
    const float* a   = (const float*)d_in[3];
    float* out = (float*)d_out;

    float* s1 = (float*)d_ws;                            // 16K f32
    float* s2 = s1 + NB * NN;                            // 16K f32
    unsigned short* Whbt = (unsigned short*)(s2 + NB * NN);  // 1M bf16 = 2 MB

    wh_kernel<<<NB * NN / 64, 256, 0, stream>>>(h, W, a, Whbt, s1, s2);
    attn_kernel<<<NB * (NN / 16), 256, 0, stream>>>(adj, Whbt, s1, s2, out);
}

// Round 4
// 234.317 us; speedup vs baseline: 1.1611x; 1.0096x over previous
//
#include <hip/hip_runtime.h>
#include <math.h>

#define NB 8
#define NN 2048
#define IN_DIM 256
#define OUT_DIM 64
#define ALPHA 0.2f

typedef __attribute__((ext_vector_type(8))) short bf16x8;
typedef __attribute__((ext_vector_type(4))) float f32x4;
typedef __attribute__((ext_vector_type(4))) int i32x4;

// float -> bf16 (RNE), bit trick (no NaN inputs here)
__device__ __forceinline__ unsigned short f2bf(float x) {
    union { float f; unsigned u; } v; v.f = x;
    unsigned r = v.u + 0x7FFF + ((v.u >> 16) & 1);
    return (unsigned short)(r >> 16);
}

// pack 2 f32 -> 2 bf16 (RNE), single HW instr; numerically == f2bf
__device__ __forceinline__ unsigned cvt_pk_bf16(float lo, float hi) {
    unsigned r;
    asm("v_cvt_pk_bf16_f32 %0, %1, %2" : "=v"(r) : "v"(lo), "v"(hi));
    return r;
}

// ---------------------------------------------------------------------------
// Kernel 1: Wh = h@W via bf16 MFMA. Outputs: Whbt (bf16, layout [b][d][j] so
// kernel-2 B-frags are 16B contiguous per lane), s1 = Wh@a1, s2 = Wh@a2.
// Grid 256 blocks x 256 thr; wave = one 16-row i-tile, block = 64 rows.
// ---------------------------------------------------------------------------
#define WT_STRIDE 264   // bf16 elems; 528B rows (16B aligned)
__global__ __launch_bounds__(256) void wh_kernel(const float* __restrict__ h,
                                                 const float* __restrict__ W,
                                                 const float* __restrict__ a,
                                                 unsigned short* __restrict__ Whbt,
                                                 float* __restrict__ s1,
                                                 float* __restrict__ s2) {
    __shared__ unsigned short Wt[OUT_DIM * WT_STRIDE];   // ~33 KB
    const int t = threadIdx.x;

    // stage W (coalesced f32 reads) -> Wt[n][k] bf16
    #pragma unroll 8
    for (int rep = 0; rep < 64; ++rep) {
        const int id = rep * 256 + t;          // 0..16383
        const int k = id >> 6, n = id & 63;
        Wt[n * WT_STRIDE + k] = f2bf(W[id]);
    }
    __syncthreads();

    const int lane = t & 63, wv = t >> 6;
    const int m = lane & 15, quad = lane >> 4;
    const long gr0 = (long)(blockIdx.x * 4 + wv) * 16;   // global row base

    f32x4 acc[4];
    #pragma unroll
    for (int nt = 0; nt < 4; ++nt) acc[nt] = (f32x4){0.f, 0.f, 0.f, 0.f};

    #pragma unroll
    for (int ks = 0; ks < 8; ++ks) {
        const int k0 = ks * 32;
        // A-frag: h[i = gr0+m][k0 + quad*8 .. +7]  (per-lane distinct, 32B)
        const float* hp = h + (gr0 + m) * IN_DIM + k0 + quad * 8;
        const float4 ha = *(const float4*)hp;
        const float4 hb = *(const float4*)(hp + 4);
        union { bf16x8 v; unsigned u32[4]; } af;
        af.u32[0] = cvt_pk_bf16(ha.x, ha.y);
        af.u32[1] = cvt_pk_bf16(ha.z, ha.w);
        af.u32[2] = cvt_pk_bf16(hb.x, hb.y);
        af.u32[3] = cvt_pk_bf16(hb.z, hb.w);
        #pragma unroll
        for (int nt = 0; nt < 4; ++nt) {
            const bf16x8 bf_ = *(const bf16x8*)(const void*)
                &Wt[(nt * 16 + m) * WT_STRIDE + k0 + quad * 8];
            acc[nt] = __builtin_amdgcn_mfma_f32_16x16x32_bf16(af.v, bf_, acc[nt], 0, 0, 0);
        }
    }

    // ---- epilogue.  C layout: col=lane&15 (d within tile), row=quad*4+reg (i) ----
    const int b  = (int)(gr0 >> 11);
    const int ib = (int)(gr0 & 2047);          // within-batch row base

    #pragma unroll
    for (int nt = 0; nt < 4; ++nt) {
        ushort4 w4;
        w4.x = f2bf(acc[nt][0]); w4.y = f2bf(acc[nt][1]);
        w4.z = f2bf(acc[nt][2]); w4.w = f2bf(acc[nt][3]);
        *(ushort4*)&Whbt[((long)(b * OUT_DIM + nt * 16 + m) << 11) + ib + quad * 4] = w4;
    }

    float a1v[4], a2v[4];
    #pragma unroll
    for (int nt = 0; nt < 4; ++nt) {
        a1v[nt] = a[nt * 16 + m];
        a2v[nt] = a[OUT_DIM + nt * 16 + m];
    }
    #pragma unroll
    for (int reg = 0; reg < 4; ++reg) {
        float p1 = 0.f, p2 = 0.f;
        #pragma unroll
        for (int nt = 0; nt < 4; ++nt) {
            p1 += acc[nt][reg] * a1v[nt];
            p2 += acc[nt][reg] * a2v[nt];
        }
        #pragma unroll
        for (int off = 1; off < 16; off <<= 1) {
            p1 += __shfl_xor(p1, off, 64);
            p2 += __shfl_xor(p2, off, 64);
        }
        if (m == 0) {
            s1[gr0 + quad * 4 + reg] = p1;
            s2[gr0 + quad * 4 + reg] = p2;
        }
    }
}

// ---------------------------------------------------------------------------
// Kernel 2: masked softmax + P@Wh via bf16 MFMA, fully fused (R3 structure),
// with DEPTH-2 ping-pong prefetch of adj (the only HBM stream in the loop):
// coverage for the ~900-1200cy HBM latency doubles to ~2 steps x 4 waves.
// s2 / Whbt B-frags stay depth-1 (L2-hot).  Full unroll so the ping-pong
// buffers index statically (stay in registers).
// Grid: NB * (NN/16) = 1024 blocks x 256 thr (16 waves/CU).
// ---------------------------------------------------------------------------
#define AB_STRIDE 68   // f32 elems per acc row; 272B (16B aligned, bank-shift 4)
__global__ __launch_bounds__(256) void attn_kernel(const int* __restrict__ adj,
                                                   const unsigned short* __restrict__ Whbt,
                                                   const float* __restrict__ s1,
                                                   const float* __restrict__ s2,
                                                   float* __restrict__ out) {
    __shared__ float accbuf[4][16 * AB_STRIDE];   // 4 waves x 16 rows x 64 d
    __shared__ float l_lds[4][16];

    const int t = threadIdx.x, lane = t & 63, wv = t >> 6;
    const int bid = blockIdx.x;
    const int b   = bid >> 7;                 // 128 tiles per batch
    const int i0  = (bid & 127) * 16;         // within-batch row base (16 rows)
    const int jlo = wv * (NN / 4);            // this wave's 512-wide j slice

    const int m = lane & 15, quad = lane >> 4;   // MFMA lane map

    const float s1v = s1[b * NN + i0 + m];

    f32x4 acc[4];
    #pragma unroll
    for (int nt = 0; nt < 4; ++nt) acc[nt] = (f32x4){0.f, 0.f, 0.f, 0.f};
    float lacc = 0.f;

    const int* adjp = adj + (long)b * NN * NN + (long)(i0 + m) * NN + jlo + quad * 8;
    const float* s2p = s2 + b * NN + jlo + quad * 8;
    const unsigned short* wbase = Whbt + ((long)(b * OUT_DIM) << 11) + jlo + quad * 8;

    const int NSTEP = NN / 4 / 32;            // 16

    // depth-2 adj prefetch (ping-pong, statically indexed via full unroll)
    i32x4 avb[2][2];
    avb[0][0] = __builtin_nontemporal_load((const i32x4*)adjp);
    avb[0][1] = __builtin_nontemporal_load((const i32x4*)(adjp + 4));
    avb[1][0] = __builtin_nontemporal_load((const i32x4*)(adjp + 32));
    avb[1][1] = __builtin_nontemporal_load((const i32x4*)(adjp + 36));

    // depth-1 s2 / B-frag prefetch (L2-hot)
    f32x4 sv0 = *(const f32x4*)s2p;
    f32x4 sv1 = *(const f32x4*)(s2p + 4);
    bf16x8 bn[4];
    #pragma unroll
    for (int nt = 0; nt < 4; ++nt)
        bn[nt] = *(const bf16x8*)(const void*)&wbase[(long)(nt * 16 + m) << 11];

    #pragma unroll
    for (int ks = 0; ks < NSTEP; ++ks) {
        const int ph = ks & 1;

        // grab current operands
        const i32x4 a0 = avb[ph][0], a1 = avb[ph][1];
        const f32x4 t0 = sv0, t1 = sv1;
        bf16x8 bc[4];
        #pragma unroll
        for (int nt = 0; nt < 4; ++nt) bc[nt] = bn[nt];

        // issue adj prefetch for step ks+2 (dummy reload at the tail)
        const int j2 = (ks + 2 < NSTEP) ? (ks + 2) * 32 : ks * 32;
        avb[ph][0] = __builtin_nontemporal_load((const i32x4*)(adjp + j2));
        avb[ph][1] = __builtin_nontemporal_load((const i32x4*)(adjp + j2 + 4));

        // issue s2 / B-frag prefetch for step ks+1
        const int j1 = (ks + 1 < NSTEP) ? (ks + 1) * 32 : ks * 32;
        sv0 = *(const f32x4*)(s2p + j1);
        sv1 = *(const f32x4*)(s2p + j1 + 4);
        #pragma unroll
        for (int nt = 0; nt < 4; ++nt)
            bn[nt] = *(const bf16x8*)(const void*)
                &wbase[((long)(nt * 16 + m) << 11) + j1];

        // P for this lane's 8 j's, directly in A-frag order
        float p[8];
        #pragma unroll
        for (int u = 0; u < 4; ++u) {
            float e = s1v + t0[u];
            e = fmaxf(e, ALPHA * e);            // leaky_relu, branchless
            const float ex = __expf(e);
            p[u] = (a0[u] != 0) ? ex : 0.f;
        }
        #pragma unroll
        for (int u = 0; u < 4; ++u) {
            float e = s1v + t1[u];
            e = fmaxf(e, ALPHA * e);
            const float ex = __expf(e);
            p[4 + u] = (a1[u] != 0) ? ex : 0.f;
        }
        lacc += ((p[0] + p[1]) + (p[2] + p[3])) + ((p[4] + p[5]) + (p[6] + p[7]));

        union { bf16x8 v; unsigned u32[4]; } af;
        af.u32[0] = cvt_pk_bf16(p[0], p[1]);
        af.u32[1] = cvt_pk_bf16(p[2], p[3]);
        af.u32[2] = cvt_pk_bf16(p[4], p[5]);
        af.u32[3] = cvt_pk_bf16(p[6], p[7]);

        #pragma unroll
        for (int nt = 0; nt < 4; ++nt)
            acc[nt] = __builtin_amdgcn_mfma_f32_16x16x32_bf16(af.v, bc[nt], acc[nt], 0, 0, 0);
    }

    // ---- per-wave l: reduce over the 4 quads (row = m) ----
    lacc += __shfl_xor(lacc, 16, 64);
    lacc += __shfl_xor(lacc, 32, 64);
    if (quad == 0) l_lds[wv][m] = lacc;

    // ---- stage this wave's acc tile.  C layout: row=quad*4+reg, d=nt*16+m ----
    #pragma unroll
    for (int nt = 0; nt < 4; ++nt)
        #pragma unroll
        for (int reg = 0; reg < 4; ++reg)
            accbuf[wv][(quad * 4 + reg) * AB_STRIDE + nt * 16 + m] = acc[nt][reg];

    __syncthreads();

    // ---- block reduce + divide + direct out write (thread t -> 4 floats) ----
    const int row = t >> 4, d0 = (t & 15) * 4;
    f32x4 v = (f32x4){0.f, 0.f, 0.f, 0.f};
    float l = 0.f;
    #pragma unroll
    for (int w2 = 0; w2 < 4; ++w2) {
        v += *(const f32x4*)&accbuf[w2][row * AB_STRIDE + d0];
        l += l_lds[w2][row];
    }
    const float inv = 1.f / l;
    float4 o; o.x = v[0] * inv; o.y = v[1] * inv; o.z = v[2] * inv; o.w = v[3] * inv;
    *(float4*)&out[((long)(b * NN + i0 + row) << 6) + d0] = o;
}

// ---------------------------------------------------------------------------
extern "C" void kernel_launch(void* const* d_in, const int* in_sizes, int n_in,
                              void* d_out, int out_size, void* d_ws, size_t ws_size,
                              hipStream_t stream) {
    const float* h   = (const float*)d_in[0];
    const int*   adj = (const int*)d_in[1];
    const float* W   = (const float*)d_in[2];
    const float* a   = (const float*)d_in[3];
    float* out = (float*)d_out;

    float* s1 = (float*)d_ws;                            // 16K f32
    float* s2 = s1 + NB * NN;                            // 16K f32
    unsigned short* Whbt = (unsigned short*)(s2 + NB * NN);  // 1M bf16 = 2 MB

    wh_kernel<<<NB * NN / 64, 256, 0, stream>>>(h, W, a, Whbt, s1, s2);
    attn_kernel<<<NB * (NN / 16), 256, 0, stream>>>(adj, Whbt, s1, s2, out);
}